// Round 9
// baseline (589.472 us; speedup 1.0000x reference)
//
#include <hip/hip_runtime.h>

#define NN    100000
#define NE    3200000
#define DIMK  512
#define HIDN  16
#define NCLS  64
#define NBUCK 391        // ceil(NN / 256) coarse buckets (dest >> 8)
#define NBLK  512        // coarse-pass chunks
#define CHUNK 6250       // NE / NBLK exactly
#define BCAP  10240      // per-bucket edge cap (mean 8192, sigma ~90 -> >20 sigma)

// ---- threefry2x32-20, JAX partitionable 32-bit path: bits = x0_final ^ x1_final,
// key=(0,42), counter=(0, i). Verified (absmax 0.031).
__device__ __forceinline__ unsigned rotl32(unsigned x, int r){ return (x << r) | (x >> (32 - r)); }

__device__ __forceinline__ unsigned threefry_bits(unsigned i){
  const unsigned k0 = 0u, k1 = 42u;
  const unsigned k2 = 0x1BD11BDAu ^ k0 ^ k1;
  unsigned a = 0u + k0, b = i + k1;
#define TF_R(r) { a += b; b = rotl32(b, (r)); b ^= a; }
  TF_R(13) TF_R(15) TF_R(26) TF_R(6)  a += k1; b += k2 + 1u;
  TF_R(17) TF_R(29) TF_R(16) TF_R(24) a += k2; b += k0 + 2u;
  TF_R(13) TF_R(15) TF_R(26) TF_R(6)  a += k0; b += k1 + 3u;
  TF_R(17) TF_R(29) TF_R(16) TF_R(24) a += k1; b += k2 + 4u;
  TF_R(13) TF_R(15) TF_R(26) TF_R(6)  a += k2; b += k0 + 5u;
#undef TF_R
  return a ^ b;   // keep iff !(bits & 0x80000000)
}

// ---- k_front: fused {coarse histogram + per-dest degree count} || {h1 = x@W1 raw fp16} ----
// Blocks [0,NBLK): histogram chunk + global-atomic per-dest degree (L2-resident 400KB).
// Blocks [NBLK,NBLK+1024): gemm, wave per node. Independent streams overlap.
__global__ __launch_bounds__(256) void k_front(const float* __restrict__ x,
                                               const float* __restrict__ W1,
                                               const int* __restrict__ col,
                                               int* __restrict__ M,
                                               int* __restrict__ dcnt0,
                                               _Float16* __restrict__ h1){
  __shared__ int h[NBUCK];
  if (blockIdx.x < NBLK){
    const int blk = blockIdx.x, t = threadIdx.x;
    for (int q = t; q < NBUCK; q += 256) h[q] = 0;
    __syncthreads();
    const int e0 = blk * CHUNK;
    for (int i = t; i < CHUNK; i += 256){
      int c = col[e0 + i];
      atomicAdd(&h[c >> 8], 1);        // LDS: coarse histogram
      atomicAdd(&dcnt0[c], 1);         // global: per-dest degree (L2-resident)
    }
    __syncthreads();
    for (int q = t; q < NBUCK; q += 256) M[blk * NBUCK + q] = h[q];
    return;
  }
  // ---- gemm: raw h1 (dis applied later at gather time) ----
  const int lane = threadIdx.x & 63;
  const int wid  = (blockIdx.x - NBLK) * 4 + (threadIdx.x >> 6);
  const int nw   = 1024 * 4;
  const bool s5 = (lane & 32) != 0;
  const bool s4 = (lane & 16) != 0;
  const bool s3 = (lane & 8)  != 0;
  const bool s2 = (lane & 4)  != 0;

  float4 w4[8][4];
  const float4* W1v = (const float4*)W1;
#pragma unroll
  for (int k = 0; k < 8; ++k)
#pragma unroll
    for (int jj = 0; jj < 4; ++jj)
      w4[k][jj] = W1v[(lane * 8 + k) * 4 + jj];

  for (int n = wid; n < NN; n += nw){
    const float4* xp = (const float4*)(x + (size_t)n * DIMK + lane * 8);
    float4 xa = xp[0], xb = xp[1];
    float xv[8] = {xa.x, xa.y, xa.z, xa.w, xb.x, xb.y, xb.z, xb.w};
    float acc[16];
#pragma unroll
    for (int j = 0; j < 16; ++j) acc[j] = 0.f;
#pragma unroll
    for (int k = 0; k < 8; ++k){
      float xk = xv[k];
#pragma unroll
      for (int jj = 0; jj < 4; ++jj){
        acc[jj*4+0] = fmaf(xk, w4[k][jj].x, acc[jj*4+0]);
        acc[jj*4+1] = fmaf(xk, w4[k][jj].y, acc[jj*4+1]);
        acc[jj*4+2] = fmaf(xk, w4[k][jj].z, acc[jj*4+2]);
        acc[jj*4+3] = fmaf(xk, w4[k][jj].w, acc[jj*4+3]);
      }
    }
    float t8[8];
#pragma unroll
    for (int m = 0; m < 8; ++m){
      float keep = s5 ? acc[8+m] : acc[m];
      float give = s5 ? acc[m]   : acc[8+m];
      t8[m] = keep + __shfl_xor(give, 32, 64);
    }
    float t4[4];
#pragma unroll
    for (int m = 0; m < 4; ++m){
      float keep = s4 ? t8[4+m] : t8[m];
      float give = s4 ? t8[m]   : t8[4+m];
      t4[m] = keep + __shfl_xor(give, 16, 64);
    }
    float t2[2];
#pragma unroll
    for (int m = 0; m < 2; ++m){
      float keep = s3 ? t4[2+m] : t4[m];
      float give = s3 ? t4[m]   : t4[2+m];
      t2[m] = keep + __shfl_xor(give, 8, 64);
    }
    float keep = s2 ? t2[1] : t2[0];
    float give = s2 ? t2[0] : t2[1];
    float v = keep + __shfl_xor(give, 4, 64);
    v += __shfl_xor(v, 2, 64);
    v += __shfl_xor(v, 1, 64);
    float hv = __shfl(v, (lane & 15) * 4, 64);
    if (lane < 16) h1[(size_t)n * HIDN + lane] = (_Float16)hv;   // RAW (no dis)
  }
}

// kp2: per-bucket exclusive scan across chunks; tail also computes dis from dcnt0.
__global__ __launch_bounds__(512) void kp2_rowscan(int* __restrict__ M, int* __restrict__ btot,
                                                   const int* __restrict__ dcnt0,
                                                   float* __restrict__ dis){
  __shared__ int s[512];
  const int b = blockIdx.x, t = threadIdx.x;     // b < NBUCK, t < NBLK
  const int idx = t * NBUCK + b;
  int v = M[idx];
  int x = v;
  s[t] = x; __syncthreads();
  for (int d = 1; d < 512; d <<= 1){
    int y = (t >= d) ? s[t - d] : 0;
    __syncthreads();
    x += y; s[t] = x;
    __syncthreads();
  }
  M[idx] = x - v;                 // exclusive over chunks
  if (t == 511) btot[b] = x;      // bucket total
  if (t < 256){
    int n = (b << 8) + t;
    if (n < NN) dis[n] = rsqrtf((float)(dcnt0[n] + 1));   // +1 self-loop
  }
}

// kp2b: exclusive scan of bucket totals -> bbase[NBUCK+1]
__global__ __launch_bounds__(512) void kp2b_bscan(const int* __restrict__ btot, int* __restrict__ bbase){
  __shared__ int s[512];
  const int t = threadIdx.x;
  int v = (t < NBUCK) ? btot[t] : 0;
  int x = v;
  s[t] = x; __syncthreads();
  for (int d = 1; d < 512; d <<= 1){
    int y = (t >= d) ? s[t - d] : 0;
    __syncthreads();
    x += y; s[t] = x;
    __syncthreads();
  }
  if (t < NBUCK) bbase[t] = x - v;
  if (t == NBUCK - 1) bbase[NBUCK] = x;   // == NE
}

// kp3: coarse scatter, packed (c&255)<<17 | src. Each (bucket,chunk) segment written
// by exactly one block -> lines single-XCD-owned -> L2 write-merge.
__global__ __launch_bounds__(256) void kp3_scatter(const int* __restrict__ row, const int* __restrict__ col,
                                                   const int* __restrict__ M, const int* __restrict__ bbase,
                                                   unsigned* __restrict__ coarse){
  __shared__ int cur[NBUCK];
  const int blk = blockIdx.x, t = threadIdx.x;
  for (int q = t; q < NBUCK; q += 256) cur[q] = bbase[q] + M[blk * NBUCK + q];
  __syncthreads();
  const int e0 = blk * CHUNK;
  for (int i = t; i < CHUNK; i += 256){
    int c = col[e0 + i];
    int r = row[e0 + i];
    int p = atomicAdd(&cur[c >> 8], 1);            // LDS atomic
    coarse[p] = ((unsigned)(c & 255) << 17) | (unsigned)r;
  }
}

// ---- k_sortagg1: per-bucket count+scan+rank-place in LDS + layer-1 agg fused ----
// Gathers RAW h1 and applies dis[r] at gather time (dis broadcast, L2-resident).
// Epilogue: bias/relu/dropout -> h2s16 (pre-scaled by dis for layer 2).
__global__ __launch_bounds__(1024) void k_sortagg1(const unsigned* __restrict__ coarse,
                                                   const int* __restrict__ bbase,
                                                   const _Float16* __restrict__ h1,
                                                   const float* __restrict__ dis,
                                                   const float* __restrict__ b1,
                                                   _Float16* __restrict__ h2s16){
  __shared__ int ldsCsr[BCAP];
  __shared__ int cnt[256], ofs[256], rk[256], s[256];
  const int b = blockIdx.x, t = threadIdx.x;
  const int base = bbase[b];
  const int nreg = min(bbase[b + 1] - base, BCAP);
  if (t < 256){ cnt[t] = 0; rk[t] = 0; }
  __syncthreads();
  for (int i = t; i < nreg; i += 1024)
    atomicAdd(&cnt[coarse[base + i] >> 17], 1);
  __syncthreads();
  int deg = 0, x = 0;
  if (t < 256){ deg = cnt[t]; x = deg; s[t] = x; }
  __syncthreads();
  for (int d = 1; d < 256; d <<= 1){
    int y = 0;
    if (t < 256 && t >= d) y = s[t - d];
    __syncthreads();
    if (t < 256){ x += y; s[t] = x; }
    __syncthreads();
  }
  if (t < 256) ofs[t] = x - deg;
  __syncthreads();
  for (int i = t; i < nreg; i += 1024){
    unsigned p = coarse[base + i];
    int l = p >> 17;
    int q = atomicAdd(&rk[l], 1);
    ldsCsr[ofs[l] + q] = (int)(p & 0x1FFFFu);
  }
  __syncthreads();
  // aggregation: 64 groups x 16 feature-lanes; 4 dests per group; unroll-4
  const int g = t >> 4, j = t & 15;
  for (int d = g; d < 256; d += 64){
    const int n = (b << 8) + d;
    if (n >= NN) break;
    const int st = ofs[d], cn = cnt[d];
    float acc = 0.f;
    int i = 0;
    for (; i + 4 <= cn; i += 4){
      int r0 = ldsCsr[st + i],     r1 = ldsCsr[st + i + 1];
      int r2 = ldsCsr[st + i + 2], r3 = ldsCsr[st + i + 3];
      float d0 = dis[r0], d1 = dis[r1], d2 = dis[r2], d3 = dis[r3];
      float a0 = (float)h1[r0 * HIDN + j], a1 = (float)h1[r1 * HIDN + j];
      float a2 = (float)h1[r2 * HIDN + j], a3 = (float)h1[r3 * HIDN + j];
      acc += d0 * a0 + d1 * a1 + d2 * a2 + d3 * a3;
    }
    for (; i < cn; ++i){
      int r0 = ldsCsr[st + i];
      acc += dis[r0] * (float)h1[r0 * HIDN + j];
    }
    float dn = dis[n];
    float v = fmaf(dn, acc + dn * (float)h1[(size_t)n * HIDN + j], b1[j]);
    v = fmaxf(v, 0.f);
    unsigned bits = threefry_bits((unsigned)(n * HIDN + j));
    float kept = (bits & 0x80000000u) ? 0.f : v * 2.f;   // /(1-p) = *2
    h2s16[(size_t)n * HIDN + j] = (_Float16)(kept * dn);  // pre-scale for layer 2
  }
}

// ---- k_agg2b: per-bucket count+scan+rank-place + layer-2 agg + W2 + log_softmax ----
__global__ __launch_bounds__(1024) void k_agg2b(const unsigned* __restrict__ coarse,
                                                const int* __restrict__ bbase,
                                                const _Float16* __restrict__ h2s16,
                                                const float* __restrict__ dis,
                                                const float* __restrict__ W2,
                                                const float* __restrict__ b2,
                                                float* __restrict__ out){
  __shared__ int ldsCsr[BCAP];
  __shared__ int cnt[256], ofs[256], rk[256], s[256];
  __shared__ float accT[256 * HIDN];
  const int b = blockIdx.x, t = threadIdx.x;
  const int base = bbase[b];
  const int nreg = min(bbase[b + 1] - base, BCAP);
  if (t < 256){ cnt[t] = 0; rk[t] = 0; }
  __syncthreads();
  for (int i = t; i < nreg; i += 1024)
    atomicAdd(&cnt[coarse[base + i] >> 17], 1);
  __syncthreads();
  int deg = 0, x = 0;
  if (t < 256){ deg = cnt[t]; x = deg; s[t] = x; }
  __syncthreads();
  for (int d = 1; d < 256; d <<= 1){
    int y = 0;
    if (t < 256 && t >= d) y = s[t - d];
    __syncthreads();
    if (t < 256){ x += y; s[t] = x; }
    __syncthreads();
  }
  if (t < 256) ofs[t] = x - deg;
  __syncthreads();
  for (int i = t; i < nreg; i += 1024){
    unsigned p = coarse[base + i];
    int l = p >> 17;
    int q = atomicAdd(&rk[l], 1);
    ldsCsr[ofs[l] + q] = (int)(p & 0x1FFFFu);
  }
  __syncthreads();
  // aggregation into registers, then exclusive LDS tile (no atomics); unroll-4
  const int g = t >> 4, j = t & 15;
  for (int d = g; d < 256; d += 64){
    const int n = (b << 8) + d;
    float acc = 0.f;
    if (n < NN){
      const int st = ofs[d], cn = cnt[d];
      int i = 0;
      for (; i + 4 <= cn; i += 4){
        int r0 = ldsCsr[st + i],     r1 = ldsCsr[st + i + 1];
        int r2 = ldsCsr[st + i + 2], r3 = ldsCsr[st + i + 3];
        acc += (float)h2s16[r0 * HIDN + j] + (float)h2s16[r1 * HIDN + j]
             + (float)h2s16[r2 * HIDN + j] + (float)h2s16[r3 * HIDN + j];
      }
      for (; i < cn; ++i) acc += (float)h2s16[ldsCsr[st + i] * HIDN + j];
    }
    accT[d * HIDN + j] = acc;
  }
  __syncthreads();
  // epilogue: 16 waves x 16 dests each; lane = class
  const int lane = t & 63, w = t >> 6;
  float wc[16];
#pragma unroll
  for (int k = 0; k < 16; ++k) wc[k] = W2[k * NCLS + lane];
  const float bb = b2[lane];
  for (int d = w; d < 256; d += 16){
    int n = (b << 8) + d;
    if (n >= NN) continue;                   // wave-uniform
    float dn = dis[n];
    int jl = lane & 15;
    float aggj = dn * (accT[d * HIDN + jl] + (float)h2s16[(size_t)n * HIDN + jl]);
    float s2v = bb;
#pragma unroll
    for (int k = 0; k < 16; ++k) s2v = fmaf(__shfl(aggj, k, 64), wc[k], s2v);
    float m2 = s2v;
#pragma unroll
    for (int dd = 32; dd; dd >>= 1) m2 = fmaxf(m2, __shfl_xor(m2, dd, 64));
    float ex = __expf(s2v - m2);
    float sum = ex;
#pragma unroll
    for (int dd = 32; dd; dd >>= 1) sum += __shfl_xor(sum, dd, 64);
    out[(size_t)n * NCLS + lane] = (s2v - m2) - __logf(sum);
  }
}

// ---------------- launch ----------------
extern "C" void kernel_launch(void* const* d_in, const int* in_sizes, int n_in,
                              void* d_out, int out_size, void* d_ws, size_t ws_size,
                              hipStream_t stream){
  const float* x  = (const float*)d_in[0];
  const int*   ei = (const int*)  d_in[1];
  const float* W1 = (const float*)d_in[2];
  const float* b1 = (const float*)d_in[3];
  const float* W2 = (const float*)d_in[4];
  const float* b2 = (const float*)d_in[5];
  float* out = (float*)d_out;
  const int* row = ei;          // sources
  const int* col = ei + NE;     // destinations

  char* ws = (char*)d_ws;
  int*       M      = (int*)      (ws + 0);          // 800,768 B  coarse matrix
  int*       btot   = (int*)      (ws + 800768);     // 1.6 KB
  int*       bbase  = (int*)      (ws + 802368);     // 1.6 KB
  int*       dcnt0  = (int*)      (ws + 803968);     // 400 KB  per-dest degree
  float*     dis    = (float*)    (ws + 1203968);    // 400 KB
  unsigned*  coarse = (unsigned*) (ws + 1603968);    // 12.8 MB bucket-binned edges
  _Float16*  h1     = (_Float16*) (ws + 14403968);   // 3.2 MB  raw x@W1
  _Float16*  h2s16  = (_Float16*) (ws + 17603968);   // 3.2 MB  dropout(relu(l1))*dis

  hipMemsetAsync(dcnt0, 0, NN * sizeof(int), stream);
  k_front    <<<NBLK + 1024, 256, 0, stream>>>(x, W1, col, M, dcnt0, h1);
  kp2_rowscan<<<NBUCK, 512, 0, stream>>>(M, btot, dcnt0, dis);
  kp2b_bscan <<<1, 512, 0, stream>>>(btot, bbase);
  kp3_scatter<<<NBLK, 256, 0, stream>>>(row, col, M, bbase, coarse);
  k_sortagg1 <<<NBUCK, 1024, 0, stream>>>(coarse, bbase, h1, dis, b1, h2s16);
  k_agg2b    <<<NBUCK, 1024, 0, stream>>>(coarse, bbase, h2s16, dis, W2, b2, out);
}